// Round 5
// baseline (352.074 us; speedup 1.0000x reference)
//
#include <hip/hip_runtime.h>

typedef __attribute__((ext_vector_type(8))) short short8;
typedef __attribute__((ext_vector_type(4))) float floatx4;

// ws layout (ushort element offsets):
static constexpr size_t QOFF = 0;           // Q bf16 scaled [256][512][64]
static constexpr size_t KOFF = 8388608;     // K bf16 [256][512][64]
static constexpr size_t VTOFF = 16777216;   // V^T bf16 [256][64][512]
static constexpr size_t RBOFF = 25165824;   // rel bf16 [1025][64]
static constexpr size_t XBOFF = 25231424;   // X bf16 [16384][512]
static constexpr size_t WTOFF = 33620032;   // Wqkv^T bf16 [1536][512]
static constexpr size_t WOTOFF = 34406464;  // Wout^T bf16 [512][512]
static constexpr size_t OBOFF = 34668608;   // O bf16 [16384][512]

__device__ inline unsigned short f2b(float f) {  // RNE fp32->bf16
  unsigned int u = __float_as_uint(f);
  u += 0x7fffu + ((u >> 16) & 1u);
  return (unsigned short)(u >> 16);
}

// ---------------------------------------------------------------------------
// Converters
// ---------------------------------------------------------------------------
__global__ void rel_cvt(const float* __restrict__ rel, unsigned short* __restrict__ dst) {
  int i = blockIdx.x * 256 + threadIdx.x;
  if (i < 65600) dst[i] = f2b(rel[i]);
}

__global__ __launch_bounds__(256) void x_cvt(const float* __restrict__ in,
                                             unsigned short* __restrict__ dst) {
  size_t i8 = ((size_t)blockIdx.x * 256 + threadIdx.x) * 8;
  float4 a = *(const float4*)(in + i8);
  float4 b = *(const float4*)(in + i8 + 4);
  unsigned short t[8] = {f2b(a.x), f2b(a.y), f2b(a.z), f2b(a.w),
                         f2b(b.x), f2b(b.y), f2b(b.z), f2b(b.w)};
  *(uint4*)(dst + i8) = *(uint4*)t;
}

// transpose+convert: in fp32 [R][C] -> out bf16 [C][R]; grid (C/64, R/64)
__global__ __launch_bounds__(256) void t_cvt(const float* __restrict__ in,
                                             unsigned short* __restrict__ out,
                                             int R, int C) {
  __shared__ float T[64 * 65];
  const int tid = threadIdx.x;
  const int c0 = blockIdx.x * 64, r0 = blockIdx.y * 64;
#pragma unroll
  for (int p = 0; p < 4; ++p) {
    int r = (tid >> 4) + p * 16, c4 = (tid & 15) * 4;
    float4 v = *(const float4*)(in + (size_t)(r0 + r) * C + c0 + c4);
    T[r * 65 + c4 + 0] = v.x;
    T[r * 65 + c4 + 1] = v.y;
    T[r * 65 + c4 + 2] = v.z;
    T[r * 65 + c4 + 3] = v.w;
  }
  __syncthreads();
#pragma unroll
  for (int p = 0; p < 4; ++p) {
    int oc = (tid >> 4) + p * 16;
    int or4 = (tid & 15) * 4;
    unsigned short t[4];
#pragma unroll
    for (int j = 0; j < 4; ++j) t[j] = f2b(T[(or4 + j) * 65 + oc]);
    *(uint2*)(out + (size_t)(c0 + oc) * R + r0 + or4) = *(uint2*)t;
  }
}

// ---------------------------------------------------------------------------
// Kernel 1: qkv = Xb @ Wt^T (bf16 MFMA), scatter to Q(scaled)/K [n][d], V^T [d][n]
// ---------------------------------------------------------------------------
__global__ __launch_bounds__(256) void qkv_mfma(const unsigned short* __restrict__ Xb,
                                                const unsigned short* __restrict__ Wt,
                                                unsigned short* __restrict__ wsb) {
  __shared__ __align__(16) unsigned short As[128 * 40];
  __shared__ __align__(16) unsigned short Bs[128 * 40];
  const int tid = threadIdx.x;
  const int w = tid >> 6, lane = tid & 63;
  const int g = lane >> 4, c = lane & 15;
  const int m0 = blockIdx.x * 128, n0 = blockIdx.y * 128;
  const int wr = (w >> 1) * 64, wc = (w & 1) * 64;
  const bool vmode = (blockIdx.y >= 8);

  floatx4 acc[4][4];
#pragma unroll
  for (int mi = 0; mi < 4; ++mi)
#pragma unroll
    for (int ni = 0; ni < 4; ++ni) acc[mi][ni] = (floatx4){0.f, 0.f, 0.f, 0.f};

  for (int kk = 0; kk < 512; kk += 32) {
    __syncthreads();
#pragma unroll
    for (int p = 0; p < 2; ++p) {
      int e = tid + 256 * p;
      int r = e >> 2, o = e & 3;
      *(uint4*)(As + r * 40 + o * 8) = *(const uint4*)(Xb + (size_t)(m0 + r) * 512 + kk + o * 8);
      *(uint4*)(Bs + r * 40 + o * 8) = *(const uint4*)(Wt + (size_t)(n0 + r) * 512 + kk + o * 8);
    }
    __syncthreads();
    short8 a[4], b[4];
#pragma unroll
    for (int mi = 0; mi < 4; ++mi) a[mi] = *(const short8*)(As + (wr + mi * 16 + c) * 40 + g * 8);
#pragma unroll
    for (int ni = 0; ni < 4; ++ni) b[ni] = *(const short8*)(Bs + (wc + ni * 16 + c) * 40 + g * 8);
    if (vmode) {
#pragma unroll
      for (int mi = 0; mi < 4; ++mi)
#pragma unroll
        for (int ni = 0; ni < 4; ++ni)
          acc[mi][ni] = __builtin_amdgcn_mfma_f32_16x16x32_bf16(b[ni], a[mi], acc[mi][ni], 0, 0, 0);
    } else {
#pragma unroll
      for (int mi = 0; mi < 4; ++mi)
#pragma unroll
        for (int ni = 0; ni < 4; ++ni)
          acc[mi][ni] = __builtin_amdgcn_mfma_f32_16x16x32_bf16(a[mi], b[ni], acc[mi][ni], 0, 0, 0);
    }
  }

  constexpr float SCL = 0.125f * 1.44269504088896340736f;  // scale*log2e (Q only)
  if (vmode) {
#pragma unroll
    for (int mi = 0; mi < 4; ++mi) {
      const int xrow = m0 + wr + mi * 16 + c;
      const int bb = xrow >> 9, nn = xrow & 511;
#pragma unroll
      for (int ni = 0; ni < 4; ++ni) {
#pragma unroll
        for (int r = 0; r < 4; ++r) {
          const int C = n0 + wc + ni * 16 + g * 4 + r;
          const int col512 = C & 511;
          const int h = col512 >> 6, d = col512 & 63;
          wsb[VTOFF + (size_t)(bb * 8 + h) * 32768 + (size_t)d * 512 + nn] = f2b(acc[mi][ni][r]);
        }
      }
    }
  } else {
    const size_t base = (blockIdx.y >= 4) ? KOFF : QOFF;
    const float scl = (blockIdx.y >= 4) ? 1.0f : SCL;
#pragma unroll
    for (int ni = 0; ni < 4; ++ni) {
      const int C = n0 + wc + ni * 16 + c;
      const int col512 = C & 511;
      const int h = col512 >> 6, d = col512 & 63;
#pragma unroll
      for (int mi = 0; mi < 4; ++mi) {
#pragma unroll
        for (int r = 0; r < 4; ++r) {
          const int xrow = m0 + wr + mi * 16 + g * 4 + r;
          wsb[base + (size_t)((xrow >> 9) * 8 + h) * 32768 + (size_t)(xrow & 511) * 64 + d] =
              f2b(acc[mi][ni][r] * scl);
        }
      }
    }
  }
}

// ---------------------------------------------------------------------------
// Kernel 2: barrier-free MFMA flash attention.
// All LDS is wave-private (Gs bias strip, Ps layout bounce); K/V/T/Q MFMA
// fragments load directly from global (L1/L2-resident). No __syncthreads
// anywhere -> waves drift freely, latency hidden by ~16 waves/CU.
// LDS 34.8 KB -> 4 blocks/CU.
// ---------------------------------------------------------------------------
__global__ __launch_bounds__(256) void attn_mfma(const unsigned short* __restrict__ wsb,
                                                 unsigned short* __restrict__ Ob) {
  __shared__ __align__(16) unsigned short Ps[64 * 72];
  __shared__ __align__(16) float Gs[4 * 16 * 100];  // per-wave [i=16][delta'=100]

  const int tid = threadIdx.x;
  const int w = tid >> 6, lane = tid & 63;
  const int g = lane >> 4, c = lane & 15;
  const int i0 = blockIdx.x * 64, bh = blockIdx.y;

  const unsigned short* Qg = wsb + QOFF + (size_t)bh * 32768 + (size_t)i0 * 64;
  const unsigned short* Kg = wsb + KOFF + (size_t)bh * 32768;
  const unsigned short* Vg = wsb + VTOFF + (size_t)bh * 32768;
  const unsigned short* Rg = wsb + RBOFF;

  // Q fragments (B-operand: rows i = i0 + w*16 + c), hoisted across chunks
  const short8 bq0 = *(const short8*)(Qg + (size_t)(w * 16 + c) * 64 + g * 8);
  const short8 bq1 = *(const short8*)(Qg + (size_t)(w * 16 + c) * 64 + 32 + g * 8);

  float* GsW = Gs + w * 1600;
  unsigned short* PsW = Ps + (w * 16 + c) * 72;

  float m_i = -1e30f, l_i = 0.f;
  floatx4 oa[4];
#pragma unroll
  for (int t = 0; t < 4; ++t) oa[t] = (floatx4){0.f, 0.f, 0.f, 0.f};

  for (int jc = 0; jc < 8; ++jc) {
    const int j0 = jc * 64;

    // G' = rel-window @ Q^T; rows delta = dbase + c + 16dd; gather needs
    // delta' in [0,79) -> 5 dt-tiles exactly. Direct global T loads.
    const int dbase = i0 - j0 + 449 + w * 16;
    const unsigned short* Trow = Rg + (size_t)(dbase + c) * 64;
#pragma unroll
    for (int dd = 0; dd < 5; ++dd) {
      short8 t0 = *(const short8*)(Trow + dd * 1024 + g * 8);
      short8 t1 = *(const short8*)(Trow + dd * 1024 + 32 + g * 8);
      floatx4 ga = (floatx4){0.f, 0.f, 0.f, 0.f};
      ga = __builtin_amdgcn_mfma_f32_16x16x32_bf16(t0, bq0, ga, 0, 0, 0);
      ga = __builtin_amdgcn_mfma_f32_16x16x32_bf16(t1, bq1, ga, 0, 0, 0);
      *(floatx4*)(GsW + c * 100 + dd * 16 + 4 * g) = ga;  // [i=c][delta']
    }

    // S' = K @ Q^T : D[m=j][n=i]; K fragments straight from global
    floatx4 s4[4];
#pragma unroll
    for (int t = 0; t < 4; ++t) {
      const unsigned short* Krow = Kg + (size_t)(j0 + t * 16 + c) * 64;
      short8 k0 = *(const short8*)(Krow + g * 8);
      short8 k1 = *(const short8*)(Krow + 32 + g * 8);
      floatx4 sa = (floatx4){0.f, 0.f, 0.f, 0.f};
      sa = __builtin_amdgcn_mfma_f32_16x16x32_bf16(k0, bq0, sa, 0, 0, 0);
      sa = __builtin_amdgcn_mfma_f32_16x16x32_bf16(k1, bq1, sa, 0, 0, 0);
      s4[t] = sa;
    }

    // Toeplitz bias gather: delta' = c - jloc + 63 in [0,79)
    const float* Grow = GsW + c * 100 + c + 63;
#pragma unroll
    for (int t = 0; t < 4; ++t)
#pragma unroll
      for (int r = 0; r < 4; ++r) s4[t][r] += Grow[-(16 * t + 4 * g + r)];

    // online softmax (base-2): one row (i = c) per lane, replicated over g
    float mx = -1e30f;
#pragma unroll
    for (int t = 0; t < 4; ++t)
      mx = fmaxf(mx, fmaxf(fmaxf(s4[t][0], s4[t][1]), fmaxf(s4[t][2], s4[t][3])));
    mx = fmaxf(mx, __shfl_xor(mx, 16));
    mx = fmaxf(mx, __shfl_xor(mx, 32));
    const float mn = fmaxf(m_i, mx);
    const float al = exp2f(m_i - mn);
    m_i = mn;
    float ls = 0.f;
#pragma unroll
    for (int t = 0; t < 4; ++t)
#pragma unroll
      for (int r = 0; r < 4; ++r) {
        float p = exp2f(s4[t][r] - mn);
        s4[t][r] = p;
        ls += p;
      }
    ls += __shfl_xor(ls, 16);
    ls += __shfl_xor(ls, 32);
    l_i = l_i * al + ls;

    // rescale O: O rows are i-local = 4g+r -> broadcast alpha from lane 4g+r
#pragma unroll
    for (int r = 0; r < 4; ++r) {
      const float ar = __shfl(al, 4 * g + r);
#pragma unroll
      for (int dt = 0; dt < 4; ++dt) oa[dt][r] *= ar;
    }

    // P store: natural [i=c][j], b64 per quad (wave-private bounce)
#pragma unroll
    for (int t = 0; t < 4; ++t) {
      unsigned short pk[4] = {f2b(s4[t][0]), f2b(s4[t][1]), f2b(s4[t][2]), f2b(s4[t][3])};
      *(uint2*)(PsW + t * 16 + 4 * g) = *(uint2*)pk;
    }

    // PV: A = P[i][j] (rows i=c from LDS), B = V^T[d][j] straight from global
    short8 ap0 = *(const short8*)(PsW + g * 8);
    short8 ap1 = *(const short8*)(PsW + 32 + g * 8);
#pragma unroll
    for (int dt = 0; dt < 4; ++dt) {
      const unsigned short* Vrow = Vg + (size_t)(dt * 16 + c) * 512 + j0;
      short8 bv0 = *(const short8*)(Vrow + g * 8);
      short8 bv1 = *(const short8*)(Vrow + 32 + g * 8);
      oa[dt] = __builtin_amdgcn_mfma_f32_16x16x32_bf16(ap0, bv0, oa[dt], 0, 0, 0);
      oa[dt] = __builtin_amdgcn_mfma_f32_16x16x32_bf16(ap1, bv1, oa[dt], 0, 0, 0);
    }
  }

  // epilogue: O rows i = i0 + w*16 + 4g + r, col d = 16dt + c; 1/l from lane 4g+r
  const int b = bh >> 3, h = bh & 7;
  const float invl = 1.0f / l_i;
#pragma unroll
  for (int r = 0; r < 4; ++r) {
    const float inv = __shfl(invl, 4 * g + r);
    const int i = i0 + w * 16 + 4 * g + r;
    const size_t rowoff = ((size_t)(b * 512 + i)) * 512 + h * 64;
#pragma unroll
    for (int dt = 0; dt < 4; ++dt) Ob[rowoff + dt * 16 + c] = f2b(oa[dt][r] * inv);
  }
}

// ---------------------------------------------------------------------------
// Kernel 3: out = Ob[16384x512] @ WoT^T + bias (bf16 MFMA, fp32 out)
// ---------------------------------------------------------------------------
__global__ __launch_bounds__(256) void out_mfma(const unsigned short* __restrict__ Ab,
                                                const unsigned short* __restrict__ Bt,
                                                const float* __restrict__ bias,
                                                float* __restrict__ out) {
  __shared__ __align__(16) unsigned short As[128 * 40];
  __shared__ __align__(16) unsigned short Bs[128 * 40];
  const int tid = threadIdx.x;
  const int w = tid >> 6, lane = tid & 63;
  const int g = lane >> 4, c = lane & 15;
  const int m0 = blockIdx.x * 128, n0 = blockIdx.y * 128;
  const int wr = (w >> 1) * 64, wc = (w & 1) * 64;

  floatx4 acc[4][4];
#pragma unroll
  for (int mi = 0; mi < 4; ++mi)
#pragma unroll
    for (int ni = 0; ni < 4; ++ni) acc[mi][ni] = (floatx4){0.f, 0.f, 0.f, 0.f};

  for (int kk = 0; kk < 512; kk += 32) {
    __syncthreads();
#pragma unroll
    for (int p = 0; p < 2; ++p) {
      int e = tid + 256 * p;
      int r = e >> 2, o = e & 3;
      *(uint4*)(As + r * 40 + o * 8) = *(const uint4*)(Ab + (size_t)(m0 + r) * 512 + kk + o * 8);
      *(uint4*)(Bs + r * 40 + o * 8) = *(const uint4*)(Bt + (size_t)(n0 + r) * 512 + kk + o * 8);
    }
    __syncthreads();
    short8 a[4], b[4];
#pragma unroll
    for (int mi = 0; mi < 4; ++mi) a[mi] = *(const short8*)(As + (wr + mi * 16 + c) * 40 + g * 8);
#pragma unroll
    for (int ni = 0; ni < 4; ++ni) b[ni] = *(const short8*)(Bs + (wc + ni * 16 + c) * 40 + g * 8);
#pragma unroll
    for (int mi = 0; mi < 4; ++mi)
#pragma unroll
      for (int ni = 0; ni < 4; ++ni)
        acc[mi][ni] = __builtin_amdgcn_mfma_f32_16x16x32_bf16(a[mi], b[ni], acc[mi][ni], 0, 0, 0);
  }

#pragma unroll
  for (int ni = 0; ni < 4; ++ni) {
    const int C = n0 + wc + ni * 16 + c;
    const float bv = bias[C];
#pragma unroll
    for (int mi = 0; mi < 4; ++mi) {
#pragma unroll
      for (int r = 0; r < 4; ++r) {
        const int m = m0 + wr + mi * 16 + g * 4 + r;
        out[(size_t)m * 512 + C] = acc[mi][ni][r] + bv;
      }
    }
  }
}

// ---------------------------------------------------------------------------
extern "C" void kernel_launch(void* const* d_in, const int* in_sizes, int n_in,
                              void* d_out, int out_size, void* d_ws, size_t ws_size,
                              hipStream_t stream) {
  const float* x = (const float*)d_in[0];      // [32,512,512]
  const float* Wqkv = (const float*)d_in[1];   // [512,1536]
  const float* rel = (const float*)d_in[2];    // [1025,64]
  const float* Wout = (const float*)d_in[3];   // [512,512]
  const float* bout = (const float*)d_in[4];   // [512]
  float* out = (float*)d_out;
  unsigned short* wsb = (unsigned short*)d_ws;

  rel_cvt<<<257, 256, 0, stream>>>(rel, wsb + RBOFF);
  x_cvt<<<4096, 256, 0, stream>>>(x, wsb + XBOFF);
  t_cvt<<<dim3(24, 8), 256, 0, stream>>>(Wqkv, wsb + WTOFF, 512, 1536);
  t_cvt<<<dim3(8, 8), 256, 0, stream>>>(Wout, wsb + WOTOFF, 512, 512);
  qkv_mfma<<<dim3(128, 12), 256, 0, stream>>>(wsb + XBOFF, wsb + WTOFF, wsb);
  attn_mfma<<<dim3(8, 256), 256, 0, stream>>>(wsb, wsb + OBOFF);
  out_mfma<<<dim3(128, 4), 256, 0, stream>>>(wsb + OBOFF, wsb + WOTOFF, bout, out);
}

// Round 6
// 247.011 us; speedup vs baseline: 1.4253x; 1.4253x over previous
//
#include <hip/hip_runtime.h>

typedef __attribute__((ext_vector_type(8))) short short8;
typedef __attribute__((ext_vector_type(4))) float floatx4;

// ws layout (ushort element offsets):
static constexpr size_t QOFF = 0;           // Q bf16 scaled [256][512][64]
static constexpr size_t KOFF = 8388608;     // K bf16 [256][512][64]
static constexpr size_t VTOFF = 16777216;   // V^T bf16 [256][64][512]
static constexpr size_t RBOFF = 25165824;   // rel bf16 [1025][64]
static constexpr size_t XBOFF = 25231424;   // X bf16 [16384][512]
static constexpr size_t WTOFF = 33620032;   // Wqkv^T bf16 [1536][512]
static constexpr size_t WOTOFF = 34406464;  // Wout^T bf16 [512][512]
static constexpr size_t OBOFF = 34668608;   // O bf16 [16384][512]

__device__ inline unsigned short f2b(float f) {  // RNE fp32->bf16
  unsigned int u = __float_as_uint(f);
  u += 0x7fffu + ((u >> 16) & 1u);
  return (unsigned short)(u >> 16);
}
__device__ inline float b2f(unsigned short h) {
  return __uint_as_float(((unsigned int)h) << 16);
}

// ---------------------------------------------------------------------------
// Kernel 0: merged prep — x_cvt | Wqkv^T cvt | Wout^T cvt | rel cvt
// grid: [0,4096) x_cvt, [4096,4288) t_cvt qkv, [4288,4352) t_cvt wout,
//       [4352,4609) rel_cvt
// ---------------------------------------------------------------------------
__global__ __launch_bounds__(256) void prep(const float* __restrict__ x,
                                            const float* __restrict__ Wqkv,
                                            const float* __restrict__ Wout,
                                            const float* __restrict__ rel,
                                            unsigned short* __restrict__ wsb) {
  __shared__ float T[64 * 65];
  const int bx = blockIdx.x;
  const int tid = threadIdx.x;
  if (bx < 4096) {  // x -> bf16
    size_t i8 = ((size_t)bx * 256 + tid) * 8;
    float4 a = *(const float4*)(x + i8);
    float4 b = *(const float4*)(x + i8 + 4);
    unsigned short t[8] = {f2b(a.x), f2b(a.y), f2b(a.z), f2b(a.w),
                           f2b(b.x), f2b(b.y), f2b(b.z), f2b(b.w)};
    *(uint4*)(wsb + XBOFF + i8) = *(uint4*)t;
  } else if (bx < 4352) {  // transpose+convert
    const bool isq = bx < 4288;
    const int z = isq ? bx - 4096 : bx - 4288;
    const int C = isq ? 1536 : 512;
    const int R = 512;
    const int c0 = (isq ? (z % 24) : (z % 8)) * 64;
    const int r0 = (isq ? (z / 24) : (z / 8)) * 64;
    const float* in = isq ? Wqkv : Wout;
    unsigned short* out = wsb + (isq ? WTOFF : WOTOFF);
#pragma unroll
    for (int p = 0; p < 4; ++p) {
      int r = (tid >> 4) + p * 16, c4 = (tid & 15) * 4;
      float4 v = *(const float4*)(in + (size_t)(r0 + r) * C + c0 + c4);
      T[r * 65 + c4 + 0] = v.x;
      T[r * 65 + c4 + 1] = v.y;
      T[r * 65 + c4 + 2] = v.z;
      T[r * 65 + c4 + 3] = v.w;
    }
    __syncthreads();
#pragma unroll
    for (int p = 0; p < 4; ++p) {
      int oc = (tid >> 4) + p * 16;
      int or4 = (tid & 15) * 4;
      unsigned short t[4];
#pragma unroll
      for (int j = 0; j < 4; ++j) t[j] = f2b(T[(or4 + j) * 65 + oc]);
      *(uint2*)(out + (size_t)(c0 + oc) * R + r0 + or4) = *(uint2*)t;
    }
  } else {  // rel -> bf16
    int i = (bx - 4352) * 256 + tid;
    if (i < 65600) wsb[RBOFF + i] = f2b(rel[i]);
  }
}

// ---------------------------------------------------------------------------
// Kernel 1: qkv = Xb @ Wt^T (bf16 MFMA) with register-prefetch pipeline.
// Scatter to Q(scaled)/K [n][d], V^T [d][n] (operand-swapped MFMA for V).
// ---------------------------------------------------------------------------
__global__ __launch_bounds__(256) void qkv_mfma(const unsigned short* __restrict__ Xb,
                                                const unsigned short* __restrict__ Wt,
                                                unsigned short* __restrict__ wsb) {
  __shared__ __align__(16) unsigned short As[128 * 40];
  __shared__ __align__(16) unsigned short Bs[128 * 40];
  const int tid = threadIdx.x;
  const int w = tid >> 6, lane = tid & 63;
  const int g = lane >> 4, c = lane & 15;
  const int m0 = blockIdx.x * 128, n0 = blockIdx.y * 128;
  const int wr = (w >> 1) * 64, wc = (w & 1) * 64;
  const bool vmode = (blockIdx.y >= 8);

  const int rA = tid >> 2, oA = tid & 3;  // staging: rows rA and rA+64

  floatx4 acc[4][4];
#pragma unroll
  for (int mi = 0; mi < 4; ++mi)
#pragma unroll
    for (int ni = 0; ni < 4; ++ni) acc[mi][ni] = (floatx4){0.f, 0.f, 0.f, 0.f};

  // prefetch k-tile 0
  uint4 pa0 = *(const uint4*)(Xb + (size_t)(m0 + rA) * 512 + oA * 8);
  uint4 pa1 = *(const uint4*)(Xb + (size_t)(m0 + rA + 64) * 512 + oA * 8);
  uint4 pb0 = *(const uint4*)(Wt + (size_t)(n0 + rA) * 512 + oA * 8);
  uint4 pb1 = *(const uint4*)(Wt + (size_t)(n0 + rA + 64) * 512 + oA * 8);

  for (int kk = 0; kk < 512; kk += 32) {
    __syncthreads();
    *(uint4*)(As + rA * 40 + oA * 8) = pa0;
    *(uint4*)(As + (rA + 64) * 40 + oA * 8) = pa1;
    *(uint4*)(Bs + rA * 40 + oA * 8) = pb0;
    *(uint4*)(Bs + (rA + 64) * 40 + oA * 8) = pb1;
    __syncthreads();
    const int kkn = (kk < 480) ? kk + 32 : kk;
    pa0 = *(const uint4*)(Xb + (size_t)(m0 + rA) * 512 + kkn + oA * 8);
    pa1 = *(const uint4*)(Xb + (size_t)(m0 + rA + 64) * 512 + kkn + oA * 8);
    pb0 = *(const uint4*)(Wt + (size_t)(n0 + rA) * 512 + kkn + oA * 8);
    pb1 = *(const uint4*)(Wt + (size_t)(n0 + rA + 64) * 512 + kkn + oA * 8);

    short8 a[4], b[4];
#pragma unroll
    for (int mi = 0; mi < 4; ++mi) a[mi] = *(const short8*)(As + (wr + mi * 16 + c) * 40 + g * 8);
#pragma unroll
    for (int ni = 0; ni < 4; ++ni) b[ni] = *(const short8*)(Bs + (wc + ni * 16 + c) * 40 + g * 8);
    if (vmode) {
#pragma unroll
      for (int mi = 0; mi < 4; ++mi)
#pragma unroll
        for (int ni = 0; ni < 4; ++ni)
          acc[mi][ni] = __builtin_amdgcn_mfma_f32_16x16x32_bf16(b[ni], a[mi], acc[mi][ni], 0, 0, 0);
    } else {
#pragma unroll
      for (int mi = 0; mi < 4; ++mi)
#pragma unroll
        for (int ni = 0; ni < 4; ++ni)
          acc[mi][ni] = __builtin_amdgcn_mfma_f32_16x16x32_bf16(a[mi], b[ni], acc[mi][ni], 0, 0, 0);
    }
  }

  constexpr float SCL = 0.125f * 1.44269504088896340736f;  // scale*log2e (Q only)
  if (vmode) {
#pragma unroll
    for (int mi = 0; mi < 4; ++mi) {
      const int xrow = m0 + wr + mi * 16 + c;
      const int bb = xrow >> 9, nn = xrow & 511;
#pragma unroll
      for (int ni = 0; ni < 4; ++ni) {
#pragma unroll
        for (int r = 0; r < 4; ++r) {
          const int C = n0 + wc + ni * 16 + g * 4 + r;
          const int col512 = C & 511;
          const int h = col512 >> 6, d = col512 & 63;
          wsb[VTOFF + (size_t)(bb * 8 + h) * 32768 + (size_t)d * 512 + nn] = f2b(acc[mi][ni][r]);
        }
      }
    }
  } else {
    const size_t base = (blockIdx.y >= 4) ? KOFF : QOFF;
    const float scl = (blockIdx.y >= 4) ? 1.0f : SCL;
#pragma unroll
    for (int ni = 0; ni < 4; ++ni) {
      const int C = n0 + wc + ni * 16 + c;
      const int col512 = C & 511;
      const int h = col512 >> 6, d = col512 & 63;
#pragma unroll
      for (int mi = 0; mi < 4; ++mi) {
#pragma unroll
        for (int r = 0; r < 4; ++r) {
          const int xrow = m0 + wr + mi * 16 + g * 4 + r;
          wsb[base + (size_t)((xrow >> 9) * 8 + h) * 32768 + (size_t)(xrow & 511) * 64 + d] =
              f2b(acc[mi][ni][r] * scl);
        }
      }
    }
  }
}

// ---------------------------------------------------------------------------
// Kernel 2: MFMA flash attention, software-pipelined.
// K/V staged via register prefetch (L2 latency overlaps previous chunk's
// compute; barrier gap contains only ds_writes). T loads hoisted ahead of the
// S phase. Gs bias strip in bf16 -> LDS 38.4 KB -> 4 blocks/CU.
// ---------------------------------------------------------------------------
__global__ __launch_bounds__(256) void attn_mfma(const unsigned short* __restrict__ wsb,
                                                 unsigned short* __restrict__ Ob) {
  __shared__ __align__(16) unsigned short Ks[64 * 72];
  __shared__ __align__(16) unsigned short Vt[64 * 72];
  __shared__ __align__(16) unsigned short Ps[64 * 72];
  __shared__ __align__(16) unsigned short Gs[4 * 16 * 84];  // bf16 per-wave [i][delta']

  const int tid = threadIdx.x;
  const int w = tid >> 6, lane = tid & 63;
  const int g = lane >> 4, c = lane & 15;
  const int i0 = blockIdx.x * 64, bh = blockIdx.y;

  const unsigned short* Qg = wsb + QOFF + (size_t)bh * 32768 + (size_t)i0 * 64;
  const unsigned short* Kg = wsb + KOFF + (size_t)bh * 32768;
  const unsigned short* Vg = wsb + VTOFF + (size_t)bh * 32768;
  const unsigned short* Rg = wsb + RBOFF;

  // Q fragments (B-operand rows i = i0 + w*16 + c), hoisted across chunks
  const short8 bq0 = *(const short8*)(Qg + (size_t)(w * 16 + c) * 64 + g * 8);
  const short8 bq1 = *(const short8*)(Qg + (size_t)(w * 16 + c) * 64 + 32 + g * 8);

  unsigned short* GsW = Gs + w * (16 * 84);
  unsigned short* PsW = Ps + (w * 16 + c) * 72;

  // staging decomposition: thread covers rows r0s and r0s+32, 8-elem group o0s
  const int r0s = tid >> 3, o0s = tid & 7;
  const int r1s = r0s + 32;

  // prefetch chunk 0 K/V into registers
  uint4 pk0 = *(const uint4*)(Kg + (size_t)r0s * 64 + o0s * 8);
  uint4 pk1 = *(const uint4*)(Kg + (size_t)r1s * 64 + o0s * 8);
  uint4 pv0 = *(const uint4*)(Vg + (size_t)r0s * 512 + o0s * 8);
  uint4 pv1 = *(const uint4*)(Vg + (size_t)r1s * 512 + o0s * 8);

  float m_i = -1e30f, l_i = 0.f;
  floatx4 oa[4];
#pragma unroll
  for (int t = 0; t < 4; ++t) oa[t] = (floatx4){0.f, 0.f, 0.f, 0.f};

  for (int jc = 0; jc < 8; ++jc) {
    const int j0 = jc * 64;
    __syncthreads();  // prior chunk's Ks/Vt reads done
    *(uint4*)(Ks + r0s * 72 + o0s * 8) = pk0;
    *(uint4*)(Ks + r1s * 72 + o0s * 8) = pk1;
    *(uint4*)(Vt + r0s * 72 + o0s * 8) = pv0;
    *(uint4*)(Vt + r1s * 72 + o0s * 8) = pv1;
    __syncthreads();  // staging visible

    // issue T loads for this chunk (latency hides behind S phase)
    const int dbase = i0 - j0 + 449 + w * 16;
    const unsigned short* Trow = Rg + (size_t)(dbase + c) * 64;
    short8 t0[5], t1[5];
#pragma unroll
    for (int dd = 0; dd < 5; ++dd) {
      t0[dd] = *(const short8*)(Trow + dd * 1024 + g * 8);
      t1[dd] = *(const short8*)(Trow + dd * 1024 + 32 + g * 8);
    }
    // prefetch next chunk's K/V (overlaps this chunk's compute)
    const int j0n = (jc < 7) ? j0 + 64 : j0;
    pk0 = *(const uint4*)(Kg + (size_t)(j0n + r0s) * 64 + o0s * 8);
    pk1 = *(const uint4*)(Kg + (size_t)(j0n + r1s) * 64 + o0s * 8);
    pv0 = *(const uint4*)(Vg + (size_t)r0s * 512 + j0n + o0s * 8);
    pv1 = *(const uint4*)(Vg + (size_t)r1s * 512 + j0n + o0s * 8);

    // S' = K @ Q^T : D[m=j][n=i]; lane (g,c): j = 16t+4g+r, i = c
    floatx4 s4[4];
#pragma unroll
    for (int t = 0; t < 4; ++t) {
      short8 k0 = *(const short8*)(Ks + (t * 16 + c) * 72 + g * 8);
      short8 k1 = *(const short8*)(Ks + (t * 16 + c) * 72 + 32 + g * 8);
      floatx4 sa = (floatx4){0.f, 0.f, 0.f, 0.f};
      sa = __builtin_amdgcn_mfma_f32_16x16x32_bf16(k0, bq0, sa, 0, 0, 0);
      sa = __builtin_amdgcn_mfma_f32_16x16x32_bf16(k1, bq1, sa, 0, 0, 0);
      s4[t] = sa;
    }

    // G' = rel-window @ Q^T -> Gs bf16 [i=c][delta'] (delta' in [0,80))
#pragma unroll
    for (int dd = 0; dd < 5; ++dd) {
      floatx4 ga = (floatx4){0.f, 0.f, 0.f, 0.f};
      ga = __builtin_amdgcn_mfma_f32_16x16x32_bf16(t0[dd], bq0, ga, 0, 0, 0);
      ga = __builtin_amdgcn_mfma_f32_16x16x32_bf16(t1[dd], bq1, ga, 0, 0, 0);
      unsigned short gk[4] = {f2b(ga[0]), f2b(ga[1]), f2b(ga[2]), f2b(ga[3])};
      *(uint2*)(GsW + c * 84 + dd * 16 + 4 * g) = *(uint2*)gk;
    }

    // Toeplitz bias gather: delta' = c - jloc + 63 in [0,79]
    const unsigned short* Grow = GsW + c * 84 + c + 63;
#pragma unroll
    for (int t = 0; t < 4; ++t)
#pragma unroll
      for (int r = 0; r < 4; ++r) s4[t][r] += b2f(Grow[-(16 * t + 4 * g + r)]);

    // online softmax (base-2): one row (i = c) per lane, replicated over g
    float mx = -1e30f;
#pragma unroll
    for (int t = 0; t < 4; ++t)
      mx = fmaxf(mx, fmaxf(fmaxf(s4[t][0], s4[t][1]), fmaxf(s4[t][2], s4[t][3])));
    mx = fmaxf(mx, __shfl_xor(mx, 16));
    mx = fmaxf(mx, __shfl_xor(mx, 32));
    const float mn = fmaxf(m_i, mx);
    const float al = exp2f(m_i - mn);
    m_i = mn;
    float ls = 0.f;
#pragma unroll
    for (int t = 0; t < 4; ++t)
#pragma unroll
      for (int r = 0; r < 4; ++r) {
        float p = exp2f(s4[t][r] - mn);
        s4[t][r] = p;
        ls += p;
      }
    ls += __shfl_xor(ls, 16);
    ls += __shfl_xor(ls, 32);
    l_i = l_i * al + ls;

    // rescale O: O rows are i-local = 4g+r -> broadcast alpha from lane 4g+r
#pragma unroll
    for (int r = 0; r < 4; ++r) {
      const float ar = __shfl(al, 4 * g + r);
#pragma unroll
      for (int dt = 0; dt < 4; ++dt) oa[dt][r] *= ar;
    }

    // P store: natural [i=c][j], b64 per quad (wave-private bounce)
#pragma unroll
    for (int t = 0; t < 4; ++t) {
      unsigned short pk[4] = {f2b(s4[t][0]), f2b(s4[t][1]), f2b(s4[t][2]), f2b(s4[t][3])};
      *(uint2*)(PsW + t * 16 + 4 * g) = *(uint2*)pk;
    }

    // PV: A = P[i][j] (rows i=c), B = V^T[d][j] from LDS
    short8 ap0 = *(const short8*)(PsW + g * 8);
    short8 ap1 = *(const short8*)(PsW + 32 + g * 8);
#pragma unroll
    for (int dt = 0; dt < 4; ++dt) {
      short8 bv0 = *(const short8*)(Vt + (dt * 16 + c) * 72 + g * 8);
      short8 bv1 = *(const short8*)(Vt + (dt * 16 + c) * 72 + 32 + g * 8);
      oa[dt] = __builtin_amdgcn_mfma_f32_16x16x32_bf16(ap0, bv0, oa[dt], 0, 0, 0);
      oa[dt] = __builtin_amdgcn_mfma_f32_16x16x32_bf16(ap1, bv1, oa[dt], 0, 0, 0);
    }
  }

  // epilogue: O rows i = i0 + w*16 + 4g + r, col d = 16dt + c; 1/l from lane 4g+r
  const int b = bh >> 3, h = bh & 7;
  const float invl = 1.0f / l_i;
#pragma unroll
  for (int r = 0; r < 4; ++r) {
    const float inv = __shfl(invl, 4 * g + r);
    const int i = i0 + w * 16 + 4 * g + r;
    const size_t rowoff = ((size_t)(b * 512 + i)) * 512 + h * 64;
#pragma unroll
    for (int dt = 0; dt < 4; ++dt) Ob[rowoff + dt * 16 + c] = f2b(oa[dt][r] * inv);
  }
}

// ---------------------------------------------------------------------------
// Kernel 3: out = Ob[16384x512] @ WoT^T + bias (bf16 MFMA, fp32 out)
// ---------------------------------------------------------------------------
__global__ __launch_bounds__(256) void out_mfma(const unsigned short* __restrict__ Ab,
                                                const unsigned short* __restrict__ Bt,
                                                const float* __restrict__ bias,
                                                float* __restrict__ out) {
  __shared__ __align__(16) unsigned short As[128 * 40];
  __shared__ __align__(16) unsigned short Bs[128 * 40];
  const int tid = threadIdx.x;
  const int w = tid >> 6, lane = tid & 63;
  const int g = lane >> 4, c = lane & 15;
  const int m0 = blockIdx.x * 128, n0 = blockIdx.y * 128;
  const int wr = (w >> 1) * 64, wc = (w & 1) * 64;

  floatx4 acc[4][4];
#pragma unroll
  for (int mi = 0; mi < 4; ++mi)
#pragma unroll
    for (int ni = 0; ni < 4; ++ni) acc[mi][ni] = (floatx4){0.f, 0.f, 0.f, 0.f};

  for (int kk = 0; kk < 512; kk += 32) {
    __syncthreads();
#pragma unroll
    for (int p = 0; p < 2; ++p) {
      int e = tid + 256 * p;
      int r = e >> 2, o = e & 3;
      *(uint4*)(As + r * 40 + o * 8) = *(const uint4*)(Ab + (size_t)(m0 + r) * 512 + kk + o * 8);
      *(uint4*)(Bs + r * 40 + o * 8) = *(const uint4*)(Bt + (size_t)(n0 + r) * 512 + kk + o * 8);
    }
    __syncthreads();
    short8 a[4], b[4];
#pragma unroll
    for (int mi = 0; mi < 4; ++mi) a[mi] = *(const short8*)(As + (wr + mi * 16 + c) * 40 + g * 8);
#pragma unroll
    for (int ni = 0; ni < 4; ++ni) b[ni] = *(const short8*)(Bs + (wc + ni * 16 + c) * 40 + g * 8);
#pragma unroll
    for (int mi = 0; mi < 4; ++mi)
#pragma unroll
      for (int ni = 0; ni < 4; ++ni)
        acc[mi][ni] = __builtin_amdgcn_mfma_f32_16x16x32_bf16(a[mi], b[ni], acc[mi][ni], 0, 0, 0);
  }

#pragma unroll
  for (int ni = 0; ni < 4; ++ni) {
    const int C = n0 + wc + ni * 16 + c;
    const float bv = bias[C];
#pragma unroll
    for (int mi = 0; mi < 4; ++mi) {
#pragma unroll
      for (int r = 0; r < 4; ++r) {
        const int m = m0 + wr + mi * 16 + g * 4 + r;
        out[(size_t)m * 512 + C] = acc[mi][ni][r] + bv;
      }
    }
  }
}

// ---------------------------------------------------------------------------
extern "C" void kernel_launch(void* const* d_in, const int* in_sizes, int n_in,
                              void* d_out, int out_size, void* d_ws, size_t ws_size,
                              hipStream_t stream) {
  const float* x = (const float*)d_in[0];      // [32,512,512]
  const float* Wqkv = (const float*)d_in[1];   // [512,1536]
  const float* rel = (const float*)d_in[2];    // [1025,64]
  const float* Wout = (const float*)d_in[3];   // [512,512]
  const float* bout = (const float*)d_in[4];   // [512]
  float* out = (float*)d_out;
  unsigned short* wsb = (unsigned short*)d_ws;

  prep<<<4609, 256, 0, stream>>>(x, Wqkv, Wout, rel, wsb);
  qkv_mfma<<<dim3(128, 12), 256, 0, stream>>>(wsb + XBOFF, wsb + WTOFF, wsb);
  attn_mfma<<<dim3(8, 256), 256, 0, stream>>>(wsb, wsb + OBOFF);
  out_mfma<<<dim3(128, 4), 256, 0, stream>>>(wsb + OBOFF, wsb + WOTOFF, bout, out);
}